// Round 11
// baseline (442.586 us; speedup 1.0000x reference)
//
#include <hip/hip_runtime.h>
#include <math.h>

#define N_NODES 100000
#define S1 50
#define S2 10
#define HID 128
#define NT 32          // nodes per block in enc2_mlp
#define AST 34         // act row stride in doubles ([k][n] rows, 16B-aligned)

// transposed fp64 weight sizes
#define W2_ELEMS   (128 * 128)     // Wt2[k][o]
#define WA_ELEMS   (129 * 128)     // Wta[k][o], k=128 row = remaining-space col
#define WB_ELEMS   (128 * 64)      // Wtb[k][o]
#define PAD_ELEMS  (W2_ELEMS + WA_ELEMS + WB_ELEMS)   // 41088

// ---------------- kernel 1: agg1 (fp64) fused with weight transpose+fp64-convert
__global__ __launch_bounds__(256) void prep_kernel(
    const float* __restrict__ feat, const int* __restrict__ neigh1,
    const float* __restrict__ W2, const float* __restrict__ w_a,
    const float* __restrict__ w_b,
    double* __restrict__ agg1d, double* __restrict__ wt)
{
    if (blockIdx.x >= 25000) {   // tail blocks: build transposed fp64 weights
        int i = (blockIdx.x - 25000) * 256 + threadIdx.x;
        if (i < W2_ELEMS) {
            int k = i >> 7, o = i & 127;
            wt[i] = (double)W2[o * 128 + k];
        } else if (i < W2_ELEMS + WA_ELEMS) {
            int j = i - W2_ELEMS;
            int k = j >> 7, o = j & 127;
            wt[i] = (double)w_a[o * 129 + k];
        } else if (i < PAD_ELEMS) {
            int j = i - W2_ELEMS - WA_ELEMS;
            int k = j >> 6, o = j & 63;
            wt[i] = (double)w_b[o * 128 + k];
        }
        return;
    }
    const int wid  = threadIdx.x >> 6;
    const int lane = threadIdx.x & 63;
    const int n = blockIdx.x * 4 + wid;
    if (n >= N_NODES) return;

    double f0 = 0.0, f1 = 0.0, f2 = 0.0;
    if (lane < S1) {
        int j = neigh1[n * S1 + lane];
        f0 = (double)feat[j * 3 + 0];
        f1 = (double)feat[j * 3 + 1];
        f2 = (double)feat[j * 3 + 2];
    } else if (lane == S1) {
        f0 = (double)feat[n * 3 + 0];
        f1 = (double)feat[n * 3 + 1];
        f2 = (double)feat[n * 3 + 2];
    }
    #pragma unroll
    for (int off = 32; off > 0; off >>= 1) {
        f0 += __shfl_down(f0, off);
        f1 += __shfl_down(f1, off);
        f2 += __shfl_down(f2, off);
    }
    if (lane == 0) {
        agg1d[n * 3 + 0] = f0 / 51.0;
        agg1d[n * 3 + 1] = f1 / 51.0;
        agg1d[n * 3 + 2] = f2 / 51.0;
    }
}

// ---------------- kernel 2: enc2 + MLP + score, fp64.
// 512 threads (8 waves), 32 nodes/block, 3125 blocks, LDS 69.6 KB -> 2 blocks/CU
// = 16 waves/CU = 4 waves/SIMD (2x r10's latency hiding; traffic unchanged).
// Wave w owns outs [16w,16w+16): each weight element still read from L2 exactly
// once per block per phase. Per thread: 2 outs x 4 nodes; per k: 1 global
// weight double2 + 2 LDS act double2 -> 8 fp64 FMAs. Acts [k][n] stride 34.
__global__ __launch_bounds__(512, 4) void enc2_mlp_kernel(
    const int* __restrict__ nodes, const int* __restrict__ neigh2,
    const double* __restrict__ agg1d,
    const float* __restrict__ W1, const double* __restrict__ wt,
    const float* __restrict__ b_a, const float* __restrict__ b_b,
    const float* __restrict__ w_c, const float* __restrict__ b_c,
    const int* __restrict__ psz, const int* __restrict__ npe,
    double* __restrict__ scoresd)
{
    __shared__ __align__(16) double sA[HID * AST];  // 34816 B, [k][n]
    __shared__ __align__(16) double sB[HID * AST];  // 34816 B; overlay sG in ph0-1
    double* sG = sB;                                // 352 rows x 4 doubles (3 used)

    const double* __restrict__ Wt2 = wt;
    const double* __restrict__ Wta = wt + W2_ELEMS;
    const double* __restrict__ Wtb = wt + W2_ELEMS + WA_ELEMS;

    const int tid  = threadIdx.x;
    const int base = blockIdx.x * NT;               // 3125*32 == 100000

    // ---- phase 0: gather 11 agg1 rows per node into sG (352 items)
    if (tid < NT * (S2 + 1)) {
        int t = tid;
        int ns = t / 11, j = t - ns * 11;
        int node = nodes[base + ns];
        int src  = (j == 0) ? node : neigh2[node * S2 + (j - 1)];
        sG[t * 4 + 0] = agg1d[src * 3 + 0];
        sG[t * 4 + 1] = agg1d[src * 3 + 1];
        sG[t * 4 + 2] = agg1d[src * 3 + 2];
    }
    __syncthreads();

    // ---- phase 1: agg2[t][n] = mean_j relu(W1[t].row_j) -> sA[t*AST+n]
    // 16 threads per node (tid&31 = node); each handles 8 t-values.
    {
        const int n = tid & 31;
        double g0[11], g1[11], g2[11];
        #pragma unroll
        for (int j = 0; j < 11; j++) {
            g0[j] = sG[(n * 11 + j) * 4 + 0];
            g1[j] = sG[(n * 11 + j) * 4 + 1];
            g2[j] = sG[(n * 11 + j) * 4 + 2];
        }
        #pragma unroll
        for (int s = 0; s < 8; s++) {
            int t = (tid >> 5) + 16 * s;            // covers 0..127
            double wx = (double)W1[t * 3 + 0];
            double wy = (double)W1[t * 3 + 1];
            double wz = (double)W1[t * 3 + 2];
            double acc = 0.0;
            #pragma unroll
            for (int j = 0; j < 11; j++)
                acc += fmax(wx * g0[j] + wy * g1[j] + wz * g2[j], 0.0);
            sA[t * AST + n] = acc / 11.0;
        }
    }
    __syncthreads();   // sG(=sB) reads done; sA complete

    const int lane = tid & 63;
    const int wave = tid >> 6;        // 0..7
    const int oq   = lane & 7;        // out-pair selector
    const int m    = lane >> 3;       // 0..7 -> nodes 4m..4m+3
    const int n0   = 4 * m;
    const int o0   = 16 * wave + 2 * oq;   // outs o0, o0+1

    // ---- phase 2: emb = relu(W2 @ agg2) : sA -> sB
    {
        double acc[2][4] = {};
        const double* __restrict__ wk = &Wt2[o0];
        const double* __restrict__ ak = &sA[n0];
        #pragma unroll 4
        for (int k = 0; k < 128; k++) {
            double2 w   = *(const double2*)&wk[k * 128];
            double2 a01 = *(const double2*)&ak[k * AST];
            double2 a23 = *(const double2*)&ak[k * AST + 2];
            acc[0][0] += w.x * a01.x; acc[0][1] += w.x * a01.y;
            acc[0][2] += w.x * a23.x; acc[0][3] += w.x * a23.y;
            acc[1][0] += w.y * a01.x; acc[1][1] += w.y * a01.y;
            acc[1][2] += w.y * a23.x; acc[1][3] += w.y * a23.y;
        }
        #pragma unroll
        for (int i = 0; i < 2; i++) {
            double2 lo = { fmax(acc[i][0], 0.0), fmax(acc[i][1], 0.0) };
            double2 hi = { fmax(acc[i][2], 0.0), fmax(acc[i][3], 0.0) };
            *(double2*)&sB[(o0 + i) * AST + n0]     = lo;
            *(double2*)&sB[(o0 + i) * AST + n0 + 2] = hi;
        }
    }
    __syncthreads();

    // ---- phase 3: xa = relu(w_a[:,:128] @ emb + w_a[:,128]*rem + b_a) : sB -> sA
    {
        double acc[2][4] = {};
        const double* __restrict__ wk = &Wta[o0];
        const double* __restrict__ ak = &sB[n0];
        #pragma unroll 4
        for (int k = 0; k < 128; k++) {
            double2 w   = *(const double2*)&wk[k * 128];
            double2 a01 = *(const double2*)&ak[k * AST];
            double2 a23 = *(const double2*)&ak[k * AST + 2];
            acc[0][0] += w.x * a01.x; acc[0][1] += w.x * a01.y;
            acc[0][2] += w.x * a23.x; acc[0][3] += w.x * a23.y;
            acc[1][0] += w.y * a01.x; acc[1][1] += w.y * a01.y;
            acc[1][2] += w.y * a23.x; acc[1][3] += w.y * a23.y;
        }
        const double rem = (double)(psz[0] - npe[0]);
        double2 rl = *(const double2*)&Wta[128 * 128 + o0];
        const double ad[2] = { rl.x * rem + (double)b_a[o0],
                               rl.y * rem + (double)b_a[o0 + 1] };
        #pragma unroll
        for (int i = 0; i < 2; i++) {
            double2 lo = { fmax(acc[i][0] + ad[i], 0.0), fmax(acc[i][1] + ad[i], 0.0) };
            double2 hi = { fmax(acc[i][2] + ad[i], 0.0), fmax(acc[i][3] + ad[i], 0.0) };
            *(double2*)&sA[(o0 + i) * AST + n0]     = lo;
            *(double2*)&sA[(o0 + i) * AST + n0 + 2] = hi;
        }
    }
    __syncthreads();

    // ---- phase 4: xb = relu(w_b @ xa + b_b) : sA -> sB  (64 outs; wave w: [8w,8w+8))
    {
        const int o = 8 * wave + oq;          // one out per thread
        double acc[4] = {};
        const double* __restrict__ wk = &Wtb[o];
        const double* __restrict__ ak = &sA[n0];
        #pragma unroll 4
        for (int k = 0; k < 128; k++) {
            double w    = wk[k * 64];
            double2 a01 = *(const double2*)&ak[k * AST];
            double2 a23 = *(const double2*)&ak[k * AST + 2];
            acc[0] += w * a01.x; acc[1] += w * a01.y;
            acc[2] += w * a23.x; acc[3] += w * a23.y;
        }
        double bb = (double)b_b[o];
        double2 lo = { fmax(acc[0] + bb, 0.0), fmax(acc[1] + bb, 0.0) };
        double2 hi = { fmax(acc[2] + bb, 0.0), fmax(acc[3] + bb, 0.0) };
        *(double2*)&sB[o * AST + n0]     = lo;
        *(double2*)&sB[o * AST + n0 + 2] = hi;
    }
    __syncthreads();

    // ---- phase 5: score = w_c . xb + b_c   (16 threads per node, 32 nodes)
    {
        const int j16 = tid & 15, ns = tid >> 4;   // ns covers 0..31 exactly
        double v = 0.0;
        #pragma unroll
        for (int r = 0; r < 4; r++)
            v += (double)w_c[j16 + 16 * r] * sB[(j16 + 16 * r) * AST + ns];
        v += __shfl_down(v, 8);
        v += __shfl_down(v, 4);
        v += __shfl_down(v, 2);
        v += __shfl_down(v, 1);
        if (j16 == 0)
            scoresd[base + ns] = v + (double)b_c[0];
    }
}

// ---------------- softmax chain: 3 kernels ----------------
__global__ __launch_bounds__(256) void reduce_max_kernel(
    const double* __restrict__ s, double* __restrict__ pmax)
{
    __shared__ double red[4];
    const int tid = threadIdx.x;
    double m = -INFINITY;
    for (int i = blockIdx.x * 256 + tid; i < N_NODES; i += gridDim.x * 256)
        m = fmax(m, s[i]);
    #pragma unroll
    for (int off = 32; off > 0; off >>= 1) m = fmax(m, __shfl_down(m, off));
    if ((tid & 63) == 0) red[tid >> 6] = m;
    __syncthreads();
    if (tid == 0)
        pmax[blockIdx.x] = fmax(fmax(red[0], red[1]), fmax(red[2], red[3]));
}

__global__ __launch_bounds__(256) void exp_sum_kernel(
    double* __restrict__ s, const double* __restrict__ pmax,
    double* __restrict__ psum)
{
    __shared__ double red[4];
    const int tid = threadIdx.x;
    double m = pmax[tid];
    #pragma unroll
    for (int off = 32; off > 0; off >>= 1) m = fmax(m, __shfl_down(m, off));
    if ((tid & 63) == 0) red[tid >> 6] = m;
    __syncthreads();
    m = fmax(fmax(red[0], red[1]), fmax(red[2], red[3]));
    __syncthreads();

    double acc = 0.0;
    for (int i = blockIdx.x * 256 + tid; i < N_NODES; i += gridDim.x * 256) {
        double e = exp(s[i] - m);
        s[i] = e;
        acc += e;
    }
    #pragma unroll
    for (int off = 32; off > 0; off >>= 1) acc += __shfl_down(acc, off);
    if ((tid & 63) == 0) red[tid >> 6] = acc;
    __syncthreads();
    if (tid == 0)
        psum[blockIdx.x] = (red[0] + red[1]) + (red[2] + red[3]);
}

__global__ __launch_bounds__(256) void scale_kernel(
    const double* __restrict__ e, const double* __restrict__ psum,
    float* __restrict__ out)
{
    __shared__ double red[4];
    const int tid = threadIdx.x;
    double acc = psum[tid];
    #pragma unroll
    for (int off = 32; off > 0; off >>= 1) acc += __shfl_down(acc, off);
    if ((tid & 63) == 0) red[tid >> 6] = acc;
    __syncthreads();
    const double invS = 1.0 / ((red[0] + red[1]) + (red[2] + red[3]));
    const int i = blockIdx.x * 256 + tid;
    if (i < N_NODES) out[i] = (float)(e[i] * invS);
}

// ---------------- launch ----------------
extern "C" void kernel_launch(void* const* d_in, const int* in_sizes, int n_in,
                              void* d_out, int out_size, void* d_ws, size_t ws_size,
                              hipStream_t stream)
{
    const int*   nodes = (const int*)  d_in[0];
    const float* feat  = (const float*)d_in[1];
    const int*   n1    = (const int*)  d_in[2];
    const int*   n2    = (const int*)  d_in[3];
    const float* W1    = (const float*)d_in[4];
    const float* W2    = (const float*)d_in[5];
    const float* w_a   = (const float*)d_in[6];
    const float* b_a   = (const float*)d_in[7];
    const float* w_b   = (const float*)d_in[8];
    const float* b_b   = (const float*)d_in[9];
    const float* w_c   = (const float*)d_in[10];
    const float* b_c   = (const float*)d_in[11];
    const int*   psz   = (const int*)  d_in[12];
    const int*   npe   = (const int*)  d_in[13];
    float* out = (float*)d_out;

    double* agg1d   = (double*)d_ws;                       // 300000
    double* scoresd = agg1d + (size_t)N_NODES * 3;         // 100000
    double* pmax    = scoresd + N_NODES;                   // 256
    double* psum    = pmax + 256;                          // 256
    double* wt      = psum + 256;                          // PAD_ELEMS fp64

    const int pad_blocks = (PAD_ELEMS + 255) / 256;        // 161
    prep_kernel<<<25000 + pad_blocks, 256, 0, stream>>>(
        feat, n1, W2, w_a, w_b, agg1d, wt);
    enc2_mlp_kernel<<<N_NODES / NT, 512, 0, stream>>>(
        nodes, n2, agg1d, W1, wt, b_a, b_b, w_c, b_c, psz, npe, scoresd);
    reduce_max_kernel<<<256, 256, 0, stream>>>(scoresd, pmax);
    exp_sum_kernel<<<256, 256, 0, stream>>>(scoresd, pmax, psum);
    scale_kernel<<<(N_NODES + 255) / 256, 256, 0, stream>>>(scoresd, psum, out);
}

// Round 12
// 428.561 us; speedup vs baseline: 1.0327x; 1.0327x over previous
//
#include <hip/hip_runtime.h>
#include <math.h>

#define N_NODES 100000
#define S1 50
#define S2 10
#define HID 128
#define NT 32          // nodes per block in enc2_mlp
#define AST 34         // act row stride in doubles ([k][n] rows, 16B-aligned)

// transposed fp64 weight sizes
#define W2_ELEMS   (128 * 128)     // Wt2[k][o]
#define WA_ELEMS   (129 * 128)     // Wta[k][o], k=128 row = remaining-space col
#define WB_ELEMS   (128 * 64)      // Wtb[k][o]
#define PAD_ELEMS  (W2_ELEMS + WA_ELEMS + WB_ELEMS)   // 41088

// ---------------- kernel 1: agg1 (fp64) fused with weight transpose+fp64-convert
__global__ __launch_bounds__(256) void prep_kernel(
    const float* __restrict__ feat, const int* __restrict__ neigh1,
    const float* __restrict__ W2, const float* __restrict__ w_a,
    const float* __restrict__ w_b,
    double* __restrict__ agg1d, double* __restrict__ wt)
{
    if (blockIdx.x >= 25000) {   // tail blocks: build transposed fp64 weights
        int i = (blockIdx.x - 25000) * 256 + threadIdx.x;
        if (i < W2_ELEMS) {
            int k = i >> 7, o = i & 127;
            wt[i] = (double)W2[o * 128 + k];
        } else if (i < W2_ELEMS + WA_ELEMS) {
            int j = i - W2_ELEMS;
            int k = j >> 7, o = j & 127;
            wt[i] = (double)w_a[o * 129 + k];
        } else if (i < PAD_ELEMS) {
            int j = i - W2_ELEMS - WA_ELEMS;
            int k = j >> 6, o = j & 63;
            wt[i] = (double)w_b[o * 128 + k];
        }
        return;
    }
    const int wid  = threadIdx.x >> 6;
    const int lane = threadIdx.x & 63;
    const int n = blockIdx.x * 4 + wid;
    if (n >= N_NODES) return;

    double f0 = 0.0, f1 = 0.0, f2 = 0.0;
    if (lane < S1) {
        int j = neigh1[n * S1 + lane];
        f0 = (double)feat[j * 3 + 0];
        f1 = (double)feat[j * 3 + 1];
        f2 = (double)feat[j * 3 + 2];
    } else if (lane == S1) {
        f0 = (double)feat[n * 3 + 0];
        f1 = (double)feat[n * 3 + 1];
        f2 = (double)feat[n * 3 + 2];
    }
    #pragma unroll
    for (int off = 32; off > 0; off >>= 1) {
        f0 += __shfl_down(f0, off);
        f1 += __shfl_down(f1, off);
        f2 += __shfl_down(f2, off);
    }
    if (lane == 0) {
        agg1d[n * 3 + 0] = f0 / 51.0;
        agg1d[n * 3 + 1] = f1 / 51.0;
        agg1d[n * 3 + 2] = f2 / 51.0;
    }
}

// ---------------- kernel 2: enc2 + MLP + score, fp64.
// 128 threads (2 waves), 32 nodes/block, 3125 blocks. Single in-place act
// buffer sX[k][n] (stride 34) + sG => 45 KB LDS -> 3 blocks/CU.
// Thread (og=tid&15, ng=tid>>4): outs {2og+32j, 2og+32j+1} j=0..3, nodes 4ng..4ng+3.
// Per k: 4 global weight double2 (lane-coalesced, read-once-per-block) +
// 2 LDS act double2 -> 32 fp64 FMAs  (2x r10's FMA-per-LDS-instr; LDS pipe
// drops below the fp64-FMA issue floor). In-place phase update: k-loop reads
// all of sX, barrier, write outputs back into sX, barrier.
__global__ __launch_bounds__(128, 1) void enc2_mlp_kernel(
    const int* __restrict__ nodes, const int* __restrict__ neigh2,
    const double* __restrict__ agg1d,
    const float* __restrict__ W1, const double* __restrict__ wt,
    const float* __restrict__ b_a, const float* __restrict__ b_b,
    const float* __restrict__ w_c, const float* __restrict__ b_c,
    const int* __restrict__ psz, const int* __restrict__ npe,
    double* __restrict__ scoresd)
{
    __shared__ __align__(16) double sX[HID * AST];      // 34816 B, acts [k][n]
    __shared__ __align__(16) double sG[NT * 11 * 4];    // 11264 B, gathered agg1

    const double* __restrict__ Wt2 = wt;
    const double* __restrict__ Wta = wt + W2_ELEMS;
    const double* __restrict__ Wtb = wt + W2_ELEMS + WA_ELEMS;

    const int tid  = threadIdx.x;
    const int base = blockIdx.x * NT;               // 3125*32 == 100000

    // ---- phase 0: gather 11 agg1 rows per node into sG (352 items)
    for (int t = tid; t < NT * (S2 + 1); t += 128) {
        int ns = t / 11, j = t - ns * 11;
        int node = nodes[base + ns];
        int src  = (j == 0) ? node : neigh2[node * S2 + (j - 1)];
        sG[t * 4 + 0] = agg1d[src * 3 + 0];
        sG[t * 4 + 1] = agg1d[src * 3 + 1];
        sG[t * 4 + 2] = agg1d[src * 3 + 2];
    }
    __syncthreads();

    // ---- phase 1: agg2[t][n] = mean_j relu(W1[t].row_j) -> sX[t*AST+n]
    // 4 threads per node (tid&31 = n); each handles 32 t-values.
    {
        const int n = tid & 31;
        double g0[11], g1[11], g2[11];
        #pragma unroll
        for (int j = 0; j < 11; j++) {
            g0[j] = sG[(n * 11 + j) * 4 + 0];
            g1[j] = sG[(n * 11 + j) * 4 + 1];
            g2[j] = sG[(n * 11 + j) * 4 + 2];
        }
        const int part = tid >> 5;                  // 0..3
        #pragma unroll
        for (int s = 0; s < 32; s++) {
            int t = part * 32 + s;
            double wx = (double)W1[t * 3 + 0];
            double wy = (double)W1[t * 3 + 1];
            double wz = (double)W1[t * 3 + 2];
            double acc = 0.0;
            #pragma unroll
            for (int j = 0; j < 11; j++)
                acc += fmax(wx * g0[j] + wy * g1[j] + wz * g2[j], 0.0);
            sX[t * AST + n] = acc / 11.0;
        }
    }
    __syncthreads();

    const int og = tid & 15;
    const int ng = tid >> 4;          // 0..7
    const int n0 = 4 * ng;
    const int o0 = 2 * og;            // out pairs at o0+32j

    // ---- phase 2: emb = relu(W2 @ agg2), in-place sX
    {
        double acc[8][4] = {};
        const double* __restrict__ wk = &Wt2[o0];
        const double* __restrict__ ak = &sX[n0];
        #pragma unroll 4
        for (int k = 0; k < 128; k++) {
            double2 w0 = *(const double2*)&wk[k * 128];
            double2 w1 = *(const double2*)&wk[k * 128 + 32];
            double2 w2v = *(const double2*)&wk[k * 128 + 64];
            double2 w3 = *(const double2*)&wk[k * 128 + 96];
            double2 a01 = *(const double2*)&ak[k * AST];
            double2 a23 = *(const double2*)&ak[k * AST + 2];
            acc[0][0] += w0.x * a01.x; acc[0][1] += w0.x * a01.y; acc[0][2] += w0.x * a23.x; acc[0][3] += w0.x * a23.y;
            acc[1][0] += w0.y * a01.x; acc[1][1] += w0.y * a01.y; acc[1][2] += w0.y * a23.x; acc[1][3] += w0.y * a23.y;
            acc[2][0] += w1.x * a01.x; acc[2][1] += w1.x * a01.y; acc[2][2] += w1.x * a23.x; acc[2][3] += w1.x * a23.y;
            acc[3][0] += w1.y * a01.x; acc[3][1] += w1.y * a01.y; acc[3][2] += w1.y * a23.x; acc[3][3] += w1.y * a23.y;
            acc[4][0] += w2v.x * a01.x; acc[4][1] += w2v.x * a01.y; acc[4][2] += w2v.x * a23.x; acc[4][3] += w2v.x * a23.y;
            acc[5][0] += w2v.y * a01.x; acc[5][1] += w2v.y * a01.y; acc[5][2] += w2v.y * a23.x; acc[5][3] += w2v.y * a23.y;
            acc[6][0] += w3.x * a01.x; acc[6][1] += w3.x * a01.y; acc[6][2] += w3.x * a23.x; acc[6][3] += w3.x * a23.y;
            acc[7][0] += w3.y * a01.x; acc[7][1] += w3.y * a01.y; acc[7][2] += w3.y * a23.x; acc[7][3] += w3.y * a23.y;
        }
        __syncthreads();   // all reads of sX done
        #pragma unroll
        for (int j = 0; j < 4; j++)
            #pragma unroll
            for (int i = 0; i < 2; i++) {
                int o = o0 + 32 * j + i, oi = 2 * j + i;
                double2 lo = { fmax(acc[oi][0], 0.0), fmax(acc[oi][1], 0.0) };
                double2 hi = { fmax(acc[oi][2], 0.0), fmax(acc[oi][3], 0.0) };
                *(double2*)&sX[o * AST + n0]     = lo;
                *(double2*)&sX[o * AST + n0 + 2] = hi;
            }
    }
    __syncthreads();

    // ---- phase 3: xa = relu(w_a[:,:128] @ emb + w_a[:,128]*rem + b_a), in-place
    {
        double acc[8][4] = {};
        const double* __restrict__ wk = &Wta[o0];
        const double* __restrict__ ak = &sX[n0];
        #pragma unroll 4
        for (int k = 0; k < 128; k++) {
            double2 w0 = *(const double2*)&wk[k * 128];
            double2 w1 = *(const double2*)&wk[k * 128 + 32];
            double2 w2v = *(const double2*)&wk[k * 128 + 64];
            double2 w3 = *(const double2*)&wk[k * 128 + 96];
            double2 a01 = *(const double2*)&ak[k * AST];
            double2 a23 = *(const double2*)&ak[k * AST + 2];
            acc[0][0] += w0.x * a01.x; acc[0][1] += w0.x * a01.y; acc[0][2] += w0.x * a23.x; acc[0][3] += w0.x * a23.y;
            acc[1][0] += w0.y * a01.x; acc[1][1] += w0.y * a01.y; acc[1][2] += w0.y * a23.x; acc[1][3] += w0.y * a23.y;
            acc[2][0] += w1.x * a01.x; acc[2][1] += w1.x * a01.y; acc[2][2] += w1.x * a23.x; acc[2][3] += w1.x * a23.y;
            acc[3][0] += w1.y * a01.x; acc[3][1] += w1.y * a01.y; acc[3][2] += w1.y * a23.x; acc[3][3] += w1.y * a23.y;
            acc[4][0] += w2v.x * a01.x; acc[4][1] += w2v.x * a01.y; acc[4][2] += w2v.x * a23.x; acc[4][3] += w2v.x * a23.y;
            acc[5][0] += w2v.y * a01.x; acc[5][1] += w2v.y * a01.y; acc[5][2] += w2v.y * a23.x; acc[5][3] += w2v.y * a23.y;
            acc[6][0] += w3.x * a01.x; acc[6][1] += w3.x * a01.y; acc[6][2] += w3.x * a23.x; acc[6][3] += w3.x * a23.y;
            acc[7][0] += w3.y * a01.x; acc[7][1] += w3.y * a01.y; acc[7][2] += w3.y * a23.x; acc[7][3] += w3.y * a23.y;
        }
        const double rem = (double)(psz[0] - npe[0]);
        __syncthreads();   // all reads of sX done
        #pragma unroll
        for (int j = 0; j < 4; j++) {
            double2 rl = *(const double2*)&Wta[128 * 128 + o0 + 32 * j];
            #pragma unroll
            for (int i = 0; i < 2; i++) {
                int o = o0 + 32 * j + i, oi = 2 * j + i;
                double ad = (i ? rl.y : rl.x) * rem + (double)b_a[o];
                double2 lo = { fmax(acc[oi][0] + ad, 0.0), fmax(acc[oi][1] + ad, 0.0) };
                double2 hi = { fmax(acc[oi][2] + ad, 0.0), fmax(acc[oi][3] + ad, 0.0) };
                *(double2*)&sX[o * AST + n0]     = lo;
                *(double2*)&sX[o * AST + n0 + 2] = hi;
            }
        }
    }
    __syncthreads();

    // ---- phase 4: xb = relu(w_b @ xa + b_b), in-place (rows 0..63)
    {
        double acc[4][4] = {};
        const double* __restrict__ wk = &Wtb[o0];
        const double* __restrict__ ak = &sX[n0];
        #pragma unroll 4
        for (int k = 0; k < 128; k++) {
            double2 w0 = *(const double2*)&wk[k * 64];
            double2 w1 = *(const double2*)&wk[k * 64 + 32];
            double2 a01 = *(const double2*)&ak[k * AST];
            double2 a23 = *(const double2*)&ak[k * AST + 2];
            acc[0][0] += w0.x * a01.x; acc[0][1] += w0.x * a01.y; acc[0][2] += w0.x * a23.x; acc[0][3] += w0.x * a23.y;
            acc[1][0] += w0.y * a01.x; acc[1][1] += w0.y * a01.y; acc[1][2] += w0.y * a23.x; acc[1][3] += w0.y * a23.y;
            acc[2][0] += w1.x * a01.x; acc[2][1] += w1.x * a01.y; acc[2][2] += w1.x * a23.x; acc[2][3] += w1.x * a23.y;
            acc[3][0] += w1.y * a01.x; acc[3][1] += w1.y * a01.y; acc[3][2] += w1.y * a23.x; acc[3][3] += w1.y * a23.y;
        }
        __syncthreads();   // all reads of sX done
        #pragma unroll
        for (int j = 0; j < 2; j++)
            #pragma unroll
            for (int i = 0; i < 2; i++) {
                int o = o0 + 32 * j + i, oi = 2 * j + i;
                double bb = (double)b_b[o];
                double2 lo = { fmax(acc[oi][0] + bb, 0.0), fmax(acc[oi][1] + bb, 0.0) };
                double2 hi = { fmax(acc[oi][2] + bb, 0.0), fmax(acc[oi][3] + bb, 0.0) };
                *(double2*)&sX[o * AST + n0]     = lo;
                *(double2*)&sX[o * AST + n0 + 2] = hi;
            }
    }
    __syncthreads();

    // ---- phase 5: score = w_c . xb + b_c   (4 threads per node, 32 nodes)
    {
        const int j4 = tid & 3, ns = tid >> 2;
        double v = 0.0;
        #pragma unroll
        for (int r = 0; r < 16; r++)
            v += (double)w_c[j4 + 4 * r] * sX[(j4 + 4 * r) * AST + ns];
        v += __shfl_down(v, 2);
        v += __shfl_down(v, 1);
        if (j4 == 0)
            scoresd[base + ns] = v + (double)b_c[0];
    }
}

// ---------------- softmax chain: 3 kernels ----------------
__global__ __launch_bounds__(256) void reduce_max_kernel(
    const double* __restrict__ s, double* __restrict__ pmax)
{
    __shared__ double red[4];
    const int tid = threadIdx.x;
    double m = -INFINITY;
    for (int i = blockIdx.x * 256 + tid; i < N_NODES; i += gridDim.x * 256)
        m = fmax(m, s[i]);
    #pragma unroll
    for (int off = 32; off > 0; off >>= 1) m = fmax(m, __shfl_down(m, off));
    if ((tid & 63) == 0) red[tid >> 6] = m;
    __syncthreads();
    if (tid == 0)
        pmax[blockIdx.x] = fmax(fmax(red[0], red[1]), fmax(red[2], red[3]));
}

__global__ __launch_bounds__(256) void exp_sum_kernel(
    double* __restrict__ s, const double* __restrict__ pmax,
    double* __restrict__ psum)
{
    __shared__ double red[4];
    const int tid = threadIdx.x;
    double m = pmax[tid];
    #pragma unroll
    for (int off = 32; off > 0; off >>= 1) m = fmax(m, __shfl_down(m, off));
    if ((tid & 63) == 0) red[tid >> 6] = m;
    __syncthreads();
    m = fmax(fmax(red[0], red[1]), fmax(red[2], red[3]));
    __syncthreads();

    double acc = 0.0;
    for (int i = blockIdx.x * 256 + tid; i < N_NODES; i += gridDim.x * 256) {
        double e = exp(s[i] - m);
        s[i] = e;
        acc += e;
    }
    #pragma unroll
    for (int off = 32; off > 0; off >>= 1) acc += __shfl_down(acc, off);
    if ((tid & 63) == 0) red[tid >> 6] = acc;
    __syncthreads();
    if (tid == 0)
        psum[blockIdx.x] = (red[0] + red[1]) + (red[2] + red[3]);
}

__global__ __launch_bounds__(256) void scale_kernel(
    const double* __restrict__ e, const double* __restrict__ psum,
    float* __restrict__ out)
{
    __shared__ double red[4];
    const int tid = threadIdx.x;
    double acc = psum[tid];
    #pragma unroll
    for (int off = 32; off > 0; off >>= 1) acc += __shfl_down(acc, off);
    if ((tid & 63) == 0) red[tid >> 6] = acc;
    __syncthreads();
    const double invS = 1.0 / ((red[0] + red[1]) + (red[2] + red[3]));
    const int i = blockIdx.x * 256 + tid;
    if (i < N_NODES) out[i] = (float)(e[i] * invS);
}

// ---------------- launch ----------------
extern "C" void kernel_launch(void* const* d_in, const int* in_sizes, int n_in,
                              void* d_out, int out_size, void* d_ws, size_t ws_size,
                              hipStream_t stream)
{
    const int*   nodes = (const int*)  d_in[0];
    const float* feat  = (const float*)d_in[1];
    const int*   n1    = (const int*)  d_in[2];
    const int*   n2    = (const int*)  d_in[3];
    const float* W1    = (const float*)d_in[4];
    const float* W2    = (const float*)d_in[5];
    const float* w_a   = (const float*)d_in[6];
    const float* b_a   = (const float*)d_in[7];
    const float* w_b   = (const float*)d_in[8];
    const float* b_b   = (const float*)d_in[9];
    const float* w_c   = (const float*)d_in[10];
    const float* b_c   = (const float*)d_in[11];
    const int*   psz   = (const int*)  d_in[12];
    const int*   npe   = (const int*)  d_in[13];
    float* out = (float*)d_out;

    double* agg1d   = (double*)d_ws;                       // 300000
    double* scoresd = agg1d + (size_t)N_NODES * 3;         // 100000
    double* pmax    = scoresd + N_NODES;                   // 256
    double* psum    = pmax + 256;                          // 256
    double* wt      = psum + 256;                          // PAD_ELEMS fp64

    const int pad_blocks = (PAD_ELEMS + 255) / 256;        // 161
    prep_kernel<<<25000 + pad_blocks, 256, 0, stream>>>(
        feat, n1, W2, w_a, w_b, agg1d, wt);
    enc2_mlp_kernel<<<N_NODES / NT, 128, 0, stream>>>(
        nodes, n2, agg1d, W1, wt, b_a, b_b, w_c, b_c, psz, npe, scoresd);
    reduce_max_kernel<<<256, 256, 0, stream>>>(scoresd, pmax);
    exp_sum_kernel<<<256, 256, 0, stream>>>(scoresd, pmax, psum);
    scale_kernel<<<(N_NODES + 255) / 256, 256, 0, stream>>>(scoresd, psum, out);
}

// Round 13
// 405.646 us; speedup vs baseline: 1.0911x; 1.0565x over previous
//
#include <hip/hip_runtime.h>
#include <math.h>

#define N_NODES 100000
#define S1 50
#define S2 10
#define HID 128
#define NT 32          // nodes per block in enc2_mlp
#define AST 34         // act row stride in doubles ([k][n] rows, 16B-aligned)

// transposed fp64 weight sizes
#define W2_ELEMS   (128 * 128)     // Wt2[k][o]
#define WA_ELEMS   (129 * 128)     // Wta[k][o], k=128 row = remaining-space col
#define WB_ELEMS   (128 * 64)      // Wtb[k][o]
#define PAD_ELEMS  (W2_ELEMS + WA_ELEMS + WB_ELEMS)   // 41088

// ---------------- kernel 1: agg1 (fp64) fused with weight transpose+fp64-convert
__global__ __launch_bounds__(256) void prep_kernel(
    const float* __restrict__ feat, const int* __restrict__ neigh1,
    const float* __restrict__ W2, const float* __restrict__ w_a,
    const float* __restrict__ w_b,
    double* __restrict__ agg1d, double* __restrict__ wt)
{
    if (blockIdx.x >= 25000) {   // tail blocks: build transposed fp64 weights
        int i = (blockIdx.x - 25000) * 256 + threadIdx.x;
        if (i < W2_ELEMS) {
            int k = i >> 7, o = i & 127;
            wt[i] = (double)W2[o * 128 + k];
        } else if (i < W2_ELEMS + WA_ELEMS) {
            int j = i - W2_ELEMS;
            int k = j >> 7, o = j & 127;
            wt[i] = (double)w_a[o * 129 + k];
        } else if (i < PAD_ELEMS) {
            int j = i - W2_ELEMS - WA_ELEMS;
            int k = j >> 6, o = j & 63;
            wt[i] = (double)w_b[o * 128 + k];
        }
        return;
    }
    const int wid  = threadIdx.x >> 6;
    const int lane = threadIdx.x & 63;
    const int n = blockIdx.x * 4 + wid;
    if (n >= N_NODES) return;

    double f0 = 0.0, f1 = 0.0, f2 = 0.0;
    if (lane < S1) {
        int j = neigh1[n * S1 + lane];
        f0 = (double)feat[j * 3 + 0];
        f1 = (double)feat[j * 3 + 1];
        f2 = (double)feat[j * 3 + 2];
    } else if (lane == S1) {
        f0 = (double)feat[n * 3 + 0];
        f1 = (double)feat[n * 3 + 1];
        f2 = (double)feat[n * 3 + 2];
    }
    #pragma unroll
    for (int off = 32; off > 0; off >>= 1) {
        f0 += __shfl_down(f0, off);
        f1 += __shfl_down(f1, off);
        f2 += __shfl_down(f2, off);
    }
    if (lane == 0) {
        agg1d[n * 3 + 0] = f0 / 51.0;
        agg1d[n * 3 + 1] = f1 / 51.0;
        agg1d[n * 3 + 2] = f2 / 51.0;
    }
}

// ---------------- kernel 2: enc2 + MLP + score, fp64.
// 128 threads (2 waves), 32 nodes/block, 3125 blocks, 45 KB LDS -> 3 blocks/CU.
// Thread (og=tid&31, ng=tid>>5): outs {2og, 2og+1, 64+2og, 64+2og+1},
// nodes {8ng..8ng+7}. Per k: 2 global weight double2 + 4 LDS act double2 ->
// 32 fp64 FMAs. Nn=8 halves register-delivered weight bytes vs r10/r12
// (the measured 208-us VMEM/L1-return wall): VMEM~104us = LDS~103us =
// FMA~104us, balanced across three separate pipes.
__global__ __launch_bounds__(128, 1) void enc2_mlp_kernel(
    const int* __restrict__ nodes, const int* __restrict__ neigh2,
    const double* __restrict__ agg1d,
    const float* __restrict__ W1, const double* __restrict__ wt,
    const float* __restrict__ b_a, const float* __restrict__ b_b,
    const float* __restrict__ w_c, const float* __restrict__ b_c,
    const int* __restrict__ psz, const int* __restrict__ npe,
    double* __restrict__ scoresd)
{
    __shared__ __align__(16) double sX[HID * AST];      // 34816 B, acts [k][n]
    __shared__ __align__(16) double sG[NT * 11 * 4];    // 11264 B, gathered agg1

    const double* __restrict__ Wt2 = wt;
    const double* __restrict__ Wta = wt + W2_ELEMS;
    const double* __restrict__ Wtb = wt + W2_ELEMS + WA_ELEMS;

    const int tid  = threadIdx.x;
    const int base = blockIdx.x * NT;               // 3125*32 == 100000

    // ---- phase 0: gather 11 agg1 rows per node into sG (352 items)
    for (int t = tid; t < NT * (S2 + 1); t += 128) {
        int ns = t / 11, j = t - ns * 11;
        int node = nodes[base + ns];
        int src  = (j == 0) ? node : neigh2[node * S2 + (j - 1)];
        sG[t * 4 + 0] = agg1d[src * 3 + 0];
        sG[t * 4 + 1] = agg1d[src * 3 + 1];
        sG[t * 4 + 2] = agg1d[src * 3 + 2];
    }
    __syncthreads();

    // ---- phase 1: agg2[t][n] = mean_j relu(W1[t].row_j) -> sX[t*AST+n]
    // 4 threads per node (tid&31 = n); each handles 32 t-values.
    {
        const int n = tid & 31;
        double g0[11], g1[11], g2[11];
        #pragma unroll
        for (int j = 0; j < 11; j++) {
            g0[j] = sG[(n * 11 + j) * 4 + 0];
            g1[j] = sG[(n * 11 + j) * 4 + 1];
            g2[j] = sG[(n * 11 + j) * 4 + 2];
        }
        const int part = tid >> 5;                  // 0..3
        #pragma unroll
        for (int s = 0; s < 32; s++) {
            int t = part * 32 + s;
            double wx = (double)W1[t * 3 + 0];
            double wy = (double)W1[t * 3 + 1];
            double wz = (double)W1[t * 3 + 2];
            double acc = 0.0;
            #pragma unroll
            for (int j = 0; j < 11; j++)
                acc += fmax(wx * g0[j] + wy * g1[j] + wz * g2[j], 0.0);
            sX[t * AST + n] = acc / 11.0;
        }
    }
    __syncthreads();

    const int og = tid & 31;          // 0..31
    const int ng = tid >> 5;          // 0..3
    const int n0 = 8 * ng;
    const int o0 = 2 * og;            // outs o0, o0+1, 64+o0, 64+o0+1

    // ---- phase 2: emb = relu(W2 @ agg2), in-place sX
    {
        double acc[4][8] = {};
        const double* __restrict__ wk = &Wt2[o0];
        const double* __restrict__ ak = &sX[n0];
        #pragma unroll 4
        for (int k = 0; k < 128; k++) {
            double2 w0 = *(const double2*)&wk[k * 128];
            double2 w1 = *(const double2*)&wk[k * 128 + 64];
            double2 a[4];
            #pragma unroll
            for (int i = 0; i < 4; i++)
                a[i] = *(const double2*)&ak[k * AST + 2 * i];
            #pragma unroll
            for (int i = 0; i < 4; i++) {
                acc[0][2*i]   += w0.x * a[i].x; acc[0][2*i+1] += w0.x * a[i].y;
                acc[1][2*i]   += w0.y * a[i].x; acc[1][2*i+1] += w0.y * a[i].y;
                acc[2][2*i]   += w1.x * a[i].x; acc[2][2*i+1] += w1.x * a[i].y;
                acc[3][2*i]   += w1.y * a[i].x; acc[3][2*i+1] += w1.y * a[i].y;
            }
        }
        __syncthreads();   // all reads of sX done
        #pragma unroll
        for (int i = 0; i < 4; i++) {
            int o = (i < 2) ? (o0 + i) : (64 + o0 + i - 2);
            #pragma unroll
            for (int j = 0; j < 4; j++) {
                double2 v = { fmax(acc[i][2*j], 0.0), fmax(acc[i][2*j+1], 0.0) };
                *(double2*)&sX[o * AST + n0 + 2 * j] = v;
            }
        }
    }
    __syncthreads();

    // ---- phase 3: xa = relu(w_a[:,:128] @ emb + w_a[:,128]*rem + b_a), in-place
    {
        double acc[4][8] = {};
        const double* __restrict__ wk = &Wta[o0];
        const double* __restrict__ ak = &sX[n0];
        #pragma unroll 4
        for (int k = 0; k < 128; k++) {
            double2 w0 = *(const double2*)&wk[k * 128];
            double2 w1 = *(const double2*)&wk[k * 128 + 64];
            double2 a[4];
            #pragma unroll
            for (int i = 0; i < 4; i++)
                a[i] = *(const double2*)&ak[k * AST + 2 * i];
            #pragma unroll
            for (int i = 0; i < 4; i++) {
                acc[0][2*i]   += w0.x * a[i].x; acc[0][2*i+1] += w0.x * a[i].y;
                acc[1][2*i]   += w0.y * a[i].x; acc[1][2*i+1] += w0.y * a[i].y;
                acc[2][2*i]   += w1.x * a[i].x; acc[2][2*i+1] += w1.x * a[i].y;
                acc[3][2*i]   += w1.y * a[i].x; acc[3][2*i+1] += w1.y * a[i].y;
            }
        }
        const double rem = (double)(psz[0] - npe[0]);
        double2 rl = *(const double2*)&Wta[128 * 128 + o0];
        double2 rh = *(const double2*)&Wta[128 * 128 + 64 + o0];
        const double ad[4] = {
            rl.x * rem + (double)b_a[o0],
            rl.y * rem + (double)b_a[o0 + 1],
            rh.x * rem + (double)b_a[64 + o0],
            rh.y * rem + (double)b_a[64 + o0 + 1] };
        __syncthreads();   // all reads of sX done
        #pragma unroll
        for (int i = 0; i < 4; i++) {
            int o = (i < 2) ? (o0 + i) : (64 + o0 + i - 2);
            #pragma unroll
            for (int j = 0; j < 4; j++) {
                double2 v = { fmax(acc[i][2*j] + ad[i], 0.0),
                              fmax(acc[i][2*j+1] + ad[i], 0.0) };
                *(double2*)&sX[o * AST + n0 + 2 * j] = v;
            }
        }
    }
    __syncthreads();

    // ---- phase 4: xb = relu(w_b @ xa + b_b), in-place (rows 0..63)
    {
        double acc[2][8] = {};
        const double* __restrict__ wk = &Wtb[o0];
        const double* __restrict__ ak = &sX[n0];
        #pragma unroll 4
        for (int k = 0; k < 128; k++) {
            double2 w = *(const double2*)&wk[k * 64];
            double2 a[4];
            #pragma unroll
            for (int i = 0; i < 4; i++)
                a[i] = *(const double2*)&ak[k * AST + 2 * i];
            #pragma unroll
            for (int i = 0; i < 4; i++) {
                acc[0][2*i]   += w.x * a[i].x; acc[0][2*i+1] += w.x * a[i].y;
                acc[1][2*i]   += w.y * a[i].x; acc[1][2*i+1] += w.y * a[i].y;
            }
        }
        __syncthreads();   // all reads of sX done
        #pragma unroll
        for (int i = 0; i < 2; i++) {
            int o = o0 + i;
            double bb = (double)b_b[o];
            #pragma unroll
            for (int j = 0; j < 4; j++) {
                double2 v = { fmax(acc[i][2*j] + bb, 0.0),
                              fmax(acc[i][2*j+1] + bb, 0.0) };
                *(double2*)&sX[o * AST + n0 + 2 * j] = v;
            }
        }
    }
    __syncthreads();

    // ---- phase 5: score = w_c . xb + b_c   (4 threads per node, 32 nodes)
    {
        const int j4 = tid & 3, ns = tid >> 2;
        double v = 0.0;
        #pragma unroll
        for (int r = 0; r < 16; r++)
            v += (double)w_c[j4 + 4 * r] * sX[(j4 + 4 * r) * AST + ns];
        v += __shfl_down(v, 2);
        v += __shfl_down(v, 1);
        if (j4 == 0)
            scoresd[base + ns] = v + (double)b_c[0];
    }
}

// ---------------- softmax chain: 3 kernels ----------------
__global__ __launch_bounds__(256) void reduce_max_kernel(
    const double* __restrict__ s, double* __restrict__ pmax)
{
    __shared__ double red[4];
    const int tid = threadIdx.x;
    double m = -INFINITY;
    for (int i = blockIdx.x * 256 + tid; i < N_NODES; i += gridDim.x * 256)
        m = fmax(m, s[i]);
    #pragma unroll
    for (int off = 32; off > 0; off >>= 1) m = fmax(m, __shfl_down(m, off));
    if ((tid & 63) == 0) red[tid >> 6] = m;
    __syncthreads();
    if (tid == 0)
        pmax[blockIdx.x] = fmax(fmax(red[0], red[1]), fmax(red[2], red[3]));
}

__global__ __launch_bounds__(256) void exp_sum_kernel(
    double* __restrict__ s, const double* __restrict__ pmax,
    double* __restrict__ psum)
{
    __shared__ double red[4];
    const int tid = threadIdx.x;
    double m = pmax[tid];
    #pragma unroll
    for (int off = 32; off > 0; off >>= 1) m = fmax(m, __shfl_down(m, off));
    if ((tid & 63) == 0) red[tid >> 6] = m;
    __syncthreads();
    m = fmax(fmax(red[0], red[1]), fmax(red[2], red[3]));
    __syncthreads();

    double acc = 0.0;
    for (int i = blockIdx.x * 256 + tid; i < N_NODES; i += gridDim.x * 256) {
        double e = exp(s[i] - m);
        s[i] = e;
        acc += e;
    }
    #pragma unroll
    for (int off = 32; off > 0; off >>= 1) acc += __shfl_down(acc, off);
    if ((tid & 63) == 0) red[tid >> 6] = acc;
    __syncthreads();
    if (tid == 0)
        psum[blockIdx.x] = (red[0] + red[1]) + (red[2] + red[3]);
}

__global__ __launch_bounds__(256) void scale_kernel(
    const double* __restrict__ e, const double* __restrict__ psum,
    float* __restrict__ out)
{
    __shared__ double red[4];
    const int tid = threadIdx.x;
    double acc = psum[tid];
    #pragma unroll
    for (int off = 32; off > 0; off >>= 1) acc += __shfl_down(acc, off);
    if ((tid & 63) == 0) red[tid >> 6] = acc;
    __syncthreads();
    const double invS = 1.0 / ((red[0] + red[1]) + (red[2] + red[3]));
    const int i = blockIdx.x * 256 + tid;
    if (i < N_NODES) out[i] = (float)(e[i] * invS);
}

// ---------------- launch ----------------
extern "C" void kernel_launch(void* const* d_in, const int* in_sizes, int n_in,
                              void* d_out, int out_size, void* d_ws, size_t ws_size,
                              hipStream_t stream)
{
    const int*   nodes = (const int*)  d_in[0];
    const float* feat  = (const float*)d_in[1];
    const int*   n1    = (const int*)  d_in[2];
    const int*   n2    = (const int*)  d_in[3];
    const float* W1    = (const float*)d_in[4];
    const float* W2    = (const float*)d_in[5];
    const float* w_a   = (const float*)d_in[6];
    const float* b_a   = (const float*)d_in[7];
    const float* w_b   = (const float*)d_in[8];
    const float* b_b   = (const float*)d_in[9];
    const float* w_c   = (const float*)d_in[10];
    const float* b_c   = (const float*)d_in[11];
    const int*   psz   = (const int*)  d_in[12];
    const int*   npe   = (const int*)  d_in[13];
    float* out = (float*)d_out;

    double* agg1d   = (double*)d_ws;                       // 300000
    double* scoresd = agg1d + (size_t)N_NODES * 3;         // 100000
    double* pmax    = scoresd + N_NODES;                   // 256
    double* psum    = pmax + 256;                          // 256
    double* wt      = psum + 256;                          // PAD_ELEMS fp64

    const int pad_blocks = (PAD_ELEMS + 255) / 256;        // 161
    prep_kernel<<<25000 + pad_blocks, 256, 0, stream>>>(
        feat, n1, W2, w_a, w_b, agg1d, wt);
    enc2_mlp_kernel<<<N_NODES / NT, 128, 0, stream>>>(
        nodes, n2, agg1d, W1, wt, b_a, b_b, w_c, b_c, psz, npe, scoresd);
    reduce_max_kernel<<<256, 256, 0, stream>>>(scoresd, pmax);
    exp_sum_kernel<<<256, 256, 0, stream>>>(scoresd, pmax, psum);
    scale_kernel<<<(N_NODES + 255) / 256, 256, 0, stream>>>(scoresd, psum, out);
}

// Round 14
// 404.992 us; speedup vs baseline: 1.0928x; 1.0016x over previous
//
#include <hip/hip_runtime.h>
#include <math.h>

#define N_NODES 100000
#define S1 50
#define S2 10
#define HID 128
#define NT 32          // nodes per block in enc2_mlp
#define AST 34         // act row stride in doubles ([k][n] rows, 16B-aligned)

// transposed fp64 weight sizes
#define W2_ELEMS   (128 * 128)     // Wt2[k][o]
#define WA_ELEMS   (129 * 128)     // Wta[k][o], k=128 row = remaining-space col
#define WB_ELEMS   (128 * 64)      // Wtb[k][o]
#define PAD_ELEMS  (W2_ELEMS + WA_ELEMS + WB_ELEMS)   // 41088

// ---------------- kernel 1: agg1 (fp64) fused with weight transpose+fp64-convert
__global__ __launch_bounds__(256) void prep_kernel(
    const float* __restrict__ feat, const int* __restrict__ neigh1,
    const float* __restrict__ W2, const float* __restrict__ w_a,
    const float* __restrict__ w_b,
    double* __restrict__ agg1d, double* __restrict__ wt)
{
    if (blockIdx.x >= 25000) {   // tail blocks: build transposed fp64 weights
        int i = (blockIdx.x - 25000) * 256 + threadIdx.x;
        if (i < W2_ELEMS) {
            int k = i >> 7, o = i & 127;
            wt[i] = (double)W2[o * 128 + k];
        } else if (i < W2_ELEMS + WA_ELEMS) {
            int j = i - W2_ELEMS;
            int k = j >> 7, o = j & 127;
            wt[i] = (double)w_a[o * 129 + k];
        } else if (i < PAD_ELEMS) {
            int j = i - W2_ELEMS - WA_ELEMS;
            int k = j >> 6, o = j & 63;
            wt[i] = (double)w_b[o * 128 + k];
        }
        return;
    }
    const int wid  = threadIdx.x >> 6;
    const int lane = threadIdx.x & 63;
    const int n = blockIdx.x * 4 + wid;
    if (n >= N_NODES) return;

    double f0 = 0.0, f1 = 0.0, f2 = 0.0;
    if (lane < S1) {
        int j = neigh1[n * S1 + lane];
        f0 = (double)feat[j * 3 + 0];
        f1 = (double)feat[j * 3 + 1];
        f2 = (double)feat[j * 3 + 2];
    } else if (lane == S1) {
        f0 = (double)feat[n * 3 + 0];
        f1 = (double)feat[n * 3 + 1];
        f2 = (double)feat[n * 3 + 2];
    }
    #pragma unroll
    for (int off = 32; off > 0; off >>= 1) {
        f0 += __shfl_down(f0, off);
        f1 += __shfl_down(f1, off);
        f2 += __shfl_down(f2, off);
    }
    if (lane == 0) {
        agg1d[n * 3 + 0] = f0 / 51.0;
        agg1d[n * 3 + 1] = f1 / 51.0;
        agg1d[n * 3 + 2] = f2 / 51.0;
    }
}

// ---------------- kernel 2: enc2 + MLP + score, fp64, software-pipelined.
// Same traffic-optimal tile as r13 (128 thr, NT=32, No=4 x Nn=8, 45 KB LDS,
// 3 blocks/CU), plus explicit rotating prefetch in the k-loops:
//   weights (global/L2, ~200 cyc)  fetched at distance 2  (~256 cyc of FMAs)
//   acts    (LDS, ~120 cyc)        fetched at distance 1  (~128 cyc of FMAs)
// Prefetch rows wrap with &127 (no OOB; dead values discarded).
__global__ __launch_bounds__(128, 1) void enc2_mlp_kernel(
    const int* __restrict__ nodes, const int* __restrict__ neigh2,
    const double* __restrict__ agg1d,
    const float* __restrict__ W1, const double* __restrict__ wt,
    const float* __restrict__ b_a, const float* __restrict__ b_b,
    const float* __restrict__ w_c, const float* __restrict__ b_c,
    const int* __restrict__ psz, const int* __restrict__ npe,
    double* __restrict__ scoresd)
{
    __shared__ __align__(16) double sX[HID * AST];      // 34816 B, acts [k][n]
    __shared__ __align__(16) double sG[NT * 11 * 4];    // 11264 B, gathered agg1

    const double* __restrict__ Wt2 = wt;
    const double* __restrict__ Wta = wt + W2_ELEMS;
    const double* __restrict__ Wtb = wt + W2_ELEMS + WA_ELEMS;

    const int tid  = threadIdx.x;
    const int base = blockIdx.x * NT;               // 3125*32 == 100000

    // ---- phase 0: gather 11 agg1 rows per node into sG (352 items)
    for (int t = tid; t < NT * (S2 + 1); t += 128) {
        int ns = t / 11, j = t - ns * 11;
        int node = nodes[base + ns];
        int src  = (j == 0) ? node : neigh2[node * S2 + (j - 1)];
        sG[t * 4 + 0] = agg1d[src * 3 + 0];
        sG[t * 4 + 1] = agg1d[src * 3 + 1];
        sG[t * 4 + 2] = agg1d[src * 3 + 2];
    }
    __syncthreads();

    // ---- phase 1: agg2[t][n] = mean_j relu(W1[t].row_j) -> sX[t*AST+n]
    {
        const int n = tid & 31;
        double g0[11], g1[11], g2[11];
        #pragma unroll
        for (int j = 0; j < 11; j++) {
            g0[j] = sG[(n * 11 + j) * 4 + 0];
            g1[j] = sG[(n * 11 + j) * 4 + 1];
            g2[j] = sG[(n * 11 + j) * 4 + 2];
        }
        const int part = tid >> 5;                  // 0..3
        #pragma unroll
        for (int s = 0; s < 32; s++) {
            int t = part * 32 + s;
            double wx = (double)W1[t * 3 + 0];
            double wy = (double)W1[t * 3 + 1];
            double wz = (double)W1[t * 3 + 2];
            double acc = 0.0;
            #pragma unroll
            for (int j = 0; j < 11; j++)
                acc += fmax(wx * g0[j] + wy * g1[j] + wz * g2[j], 0.0);
            sX[t * AST + n] = acc / 11.0;
        }
    }
    __syncthreads();

    const int og = tid & 31;          // 0..31
    const int ng = tid >> 5;          // 0..3
    const int n0 = 8 * ng;
    const int o0 = 2 * og;            // outs o0, o0+1, 64+o0, 64+o0+1

    // ---- phase 2: emb = relu(W2 @ agg2), in-place sX
    {
        double acc[4][8] = {};
        const double* __restrict__ wk = &Wt2[o0];
        const double* __restrict__ ak = &sX[n0];
        // pipeline primers: weights k=0 (current) and k=1 (next); acts k=0
        double2 wc0 = *(const double2*)&wk[0];
        double2 wc1 = *(const double2*)&wk[64];
        double2 wd0 = *(const double2*)&wk[128];
        double2 wd1 = *(const double2*)&wk[128 + 64];
        double2 ac[4];
        #pragma unroll
        for (int i = 0; i < 4; i++) ac[i] = *(const double2*)&ak[2 * i];
        #pragma unroll 4
        for (int k = 0; k < 128; k++) {
            const int k1 = (k + 1) & 127;
            const int k2 = (k + 2) & 127;
            double2 wn0 = *(const double2*)&wk[k2 * 128];
            double2 wn1 = *(const double2*)&wk[k2 * 128 + 64];
            double2 an[4];
            #pragma unroll
            for (int i = 0; i < 4; i++)
                an[i] = *(const double2*)&ak[k1 * AST + 2 * i];
            #pragma unroll
            for (int i = 0; i < 4; i++) {
                acc[0][2*i]   += wc0.x * ac[i].x; acc[0][2*i+1] += wc0.x * ac[i].y;
                acc[1][2*i]   += wc0.y * ac[i].x; acc[1][2*i+1] += wc0.y * ac[i].y;
                acc[2][2*i]   += wc1.x * ac[i].x; acc[2][2*i+1] += wc1.x * ac[i].y;
                acc[3][2*i]   += wc1.y * ac[i].x; acc[3][2*i+1] += wc1.y * ac[i].y;
            }
            wc0 = wd0; wc1 = wd1; wd0 = wn0; wd1 = wn1;
            #pragma unroll
            for (int i = 0; i < 4; i++) ac[i] = an[i];
        }
        __syncthreads();   // all reads of sX done
        #pragma unroll
        for (int i = 0; i < 4; i++) {
            int o = (i < 2) ? (o0 + i) : (64 + o0 + i - 2);
            #pragma unroll
            for (int j = 0; j < 4; j++) {
                double2 v = { fmax(acc[i][2*j], 0.0), fmax(acc[i][2*j+1], 0.0) };
                *(double2*)&sX[o * AST + n0 + 2 * j] = v;
            }
        }
    }
    __syncthreads();

    // ---- phase 3: xa = relu(w_a[:,:128] @ emb + w_a[:,128]*rem + b_a), in-place
    {
        double acc[4][8] = {};
        const double* __restrict__ wk = &Wta[o0];
        const double* __restrict__ ak = &sX[n0];
        double2 wc0 = *(const double2*)&wk[0];
        double2 wc1 = *(const double2*)&wk[64];
        double2 wd0 = *(const double2*)&wk[128];
        double2 wd1 = *(const double2*)&wk[128 + 64];
        double2 ac[4];
        #pragma unroll
        for (int i = 0; i < 4; i++) ac[i] = *(const double2*)&ak[2 * i];
        #pragma unroll 4
        for (int k = 0; k < 128; k++) {
            const int k1 = (k + 1) & 127;
            const int k2 = (k + 2) & 127;
            double2 wn0 = *(const double2*)&wk[k2 * 128];
            double2 wn1 = *(const double2*)&wk[k2 * 128 + 64];
            double2 an[4];
            #pragma unroll
            for (int i = 0; i < 4; i++)
                an[i] = *(const double2*)&ak[k1 * AST + 2 * i];
            #pragma unroll
            for (int i = 0; i < 4; i++) {
                acc[0][2*i]   += wc0.x * ac[i].x; acc[0][2*i+1] += wc0.x * ac[i].y;
                acc[1][2*i]   += wc0.y * ac[i].x; acc[1][2*i+1] += wc0.y * ac[i].y;
                acc[2][2*i]   += wc1.x * ac[i].x; acc[2][2*i+1] += wc1.x * ac[i].y;
                acc[3][2*i]   += wc1.y * ac[i].x; acc[3][2*i+1] += wc1.y * ac[i].y;
            }
            wc0 = wd0; wc1 = wd1; wd0 = wn0; wd1 = wn1;
            #pragma unroll
            for (int i = 0; i < 4; i++) ac[i] = an[i];
        }
        const double rem = (double)(psz[0] - npe[0]);
        double2 rl = *(const double2*)&Wta[128 * 128 + o0];
        double2 rh = *(const double2*)&Wta[128 * 128 + 64 + o0];
        const double ad[4] = {
            rl.x * rem + (double)b_a[o0],
            rl.y * rem + (double)b_a[o0 + 1],
            rh.x * rem + (double)b_a[64 + o0],
            rh.y * rem + (double)b_a[64 + o0 + 1] };
        __syncthreads();   // all reads of sX done
        #pragma unroll
        for (int i = 0; i < 4; i++) {
            int o = (i < 2) ? (o0 + i) : (64 + o0 + i - 2);
            #pragma unroll
            for (int j = 0; j < 4; j++) {
                double2 v = { fmax(acc[i][2*j] + ad[i], 0.0),
                              fmax(acc[i][2*j+1] + ad[i], 0.0) };
                *(double2*)&sX[o * AST + n0 + 2 * j] = v;
            }
        }
    }
    __syncthreads();

    // ---- phase 4: xb = relu(w_b @ xa + b_b), in-place (rows 0..63)
    {
        double acc[2][8] = {};
        const double* __restrict__ wk = &Wtb[o0];
        const double* __restrict__ ak = &sX[n0];
        double2 wc = *(const double2*)&wk[0];
        double2 wd = *(const double2*)&wk[64];
        double2 ac[4];
        #pragma unroll
        for (int i = 0; i < 4; i++) ac[i] = *(const double2*)&ak[2 * i];
        #pragma unroll 4
        for (int k = 0; k < 128; k++) {
            const int k1 = (k + 1) & 127;
            const int k2 = (k + 2) & 127;
            double2 wn = *(const double2*)&wk[k2 * 64];
            double2 an[4];
            #pragma unroll
            for (int i = 0; i < 4; i++)
                an[i] = *(const double2*)&ak[k1 * AST + 2 * i];
            #pragma unroll
            for (int i = 0; i < 4; i++) {
                acc[0][2*i]   += wc.x * ac[i].x; acc[0][2*i+1] += wc.x * ac[i].y;
                acc[1][2*i]   += wc.y * ac[i].x; acc[1][2*i+1] += wc.y * ac[i].y;
            }
            wc = wd; wd = wn;
            #pragma unroll
            for (int i = 0; i < 4; i++) ac[i] = an[i];
        }
        __syncthreads();   // all reads of sX done
        #pragma unroll
        for (int i = 0; i < 2; i++) {
            int o = o0 + i;
            double bb = (double)b_b[o];
            #pragma unroll
            for (int j = 0; j < 4; j++) {
                double2 v = { fmax(acc[i][2*j] + bb, 0.0),
                              fmax(acc[i][2*j+1] + bb, 0.0) };
                *(double2*)&sX[o * AST + n0 + 2 * j] = v;
            }
        }
    }
    __syncthreads();

    // ---- phase 5: score = w_c . xb + b_c   (4 threads per node, 32 nodes)
    {
        const int j4 = tid & 3, ns = tid >> 2;
        double v = 0.0;
        #pragma unroll
        for (int r = 0; r < 16; r++)
            v += (double)w_c[j4 + 4 * r] * sX[(j4 + 4 * r) * AST + ns];
        v += __shfl_down(v, 2);
        v += __shfl_down(v, 1);
        if (j4 == 0)
            scoresd[base + ns] = v + (double)b_c[0];
    }
}

// ---------------- softmax chain: 3 kernels ----------------
__global__ __launch_bounds__(256) void reduce_max_kernel(
    const double* __restrict__ s, double* __restrict__ pmax)
{
    __shared__ double red[4];
    const int tid = threadIdx.x;
    double m = -INFINITY;
    for (int i = blockIdx.x * 256 + tid; i < N_NODES; i += gridDim.x * 256)
        m = fmax(m, s[i]);
    #pragma unroll
    for (int off = 32; off > 0; off >>= 1) m = fmax(m, __shfl_down(m, off));
    if ((tid & 63) == 0) red[tid >> 6] = m;
    __syncthreads();
    if (tid == 0)
        pmax[blockIdx.x] = fmax(fmax(red[0], red[1]), fmax(red[2], red[3]));
}

__global__ __launch_bounds__(256) void exp_sum_kernel(
    double* __restrict__ s, const double* __restrict__ pmax,
    double* __restrict__ psum)
{
    __shared__ double red[4];
    const int tid = threadIdx.x;
    double m = pmax[tid];
    #pragma unroll
    for (int off = 32; off > 0; off >>= 1) m = fmax(m, __shfl_down(m, off));
    if ((tid & 63) == 0) red[tid >> 6] = m;
    __syncthreads();
    m = fmax(fmax(red[0], red[1]), fmax(red[2], red[3]));
    __syncthreads();

    double acc = 0.0;
    for (int i = blockIdx.x * 256 + tid; i < N_NODES; i += gridDim.x * 256) {
        double e = exp(s[i] - m);
        s[i] = e;
        acc += e;
    }
    #pragma unroll
    for (int off = 32; off > 0; off >>= 1) acc += __shfl_down(acc, off);
    if ((tid & 63) == 0) red[tid >> 6] = acc;
    __syncthreads();
    if (tid == 0)
        psum[blockIdx.x] = (red[0] + red[1]) + (red[2] + red[3]);
}

__global__ __launch_bounds__(256) void scale_kernel(
    const double* __restrict__ e, const double* __restrict__ psum,
    float* __restrict__ out)
{
    __shared__ double red[4];
    const int tid = threadIdx.x;
    double acc = psum[tid];
    #pragma unroll
    for (int off = 32; off > 0; off >>= 1) acc += __shfl_down(acc, off);
    if ((tid & 63) == 0) red[tid >> 6] = acc;
    __syncthreads();
    const double invS = 1.0 / ((red[0] + red[1]) + (red[2] + red[3]));
    const int i = blockIdx.x * 256 + tid;
    if (i < N_NODES) out[i] = (float)(e[i] * invS);
}

// ---------------- launch ----------------
extern "C" void kernel_launch(void* const* d_in, const int* in_sizes, int n_in,
                              void* d_out, int out_size, void* d_ws, size_t ws_size,
                              hipStream_t stream)
{
    const int*   nodes = (const int*)  d_in[0];
    const float* feat  = (const float*)d_in[1];
    const int*   n1    = (const int*)  d_in[2];
    const int*   n2    = (const int*)  d_in[3];
    const float* W1    = (const float*)d_in[4];
    const float* W2    = (const float*)d_in[5];
    const float* w_a   = (const float*)d_in[6];
    const float* b_a   = (const float*)d_in[7];
    const float* w_b   = (const float*)d_in[8];
    const float* b_b   = (const float*)d_in[9];
    const float* w_c   = (const float*)d_in[10];
    const float* b_c   = (const float*)d_in[11];
    const int*   psz   = (const int*)  d_in[12];
    const int*   npe   = (const int*)  d_in[13];
    float* out = (float*)d_out;

    double* agg1d   = (double*)d_ws;                       // 300000
    double* scoresd = agg1d + (size_t)N_NODES * 3;         // 100000
    double* pmax    = scoresd + N_NODES;                   // 256
    double* psum    = pmax + 256;                          // 256
    double* wt      = psum + 256;                          // PAD_ELEMS fp64

    const int pad_blocks = (PAD_ELEMS + 255) / 256;        // 161
    prep_kernel<<<25000 + pad_blocks, 256, 0, stream>>>(
        feat, n1, W2, w_a, w_b, agg1d, wt);
    enc2_mlp_kernel<<<N_NODES / NT, 128, 0, stream>>>(
        nodes, n2, agg1d, W1, wt, b_a, b_b, w_c, b_c, psz, npe, scoresd);
    reduce_max_kernel<<<256, 256, 0, stream>>>(scoresd, pmax);
    exp_sum_kernel<<<256, 256, 0, stream>>>(scoresd, pmax, psum);
    scale_kernel<<<(N_NODES + 255) / 256, 256, 0, stream>>>(scoresd, psum, out);
}